// Round 1
// baseline (771.479 us; speedup 1.0000x reference)
//
#include <hip/hip_runtime.h>
#include <math.h>

#define NN 100000
#define NE 1600000
#define DF 256
#define HH 64
#define TT 4
#define GG 8
#define BN_EPS 1e-5f

__device__ __forceinline__ void atomicMaxF(float* addr, float val) {
  if (val >= 0.f) atomicMax((int*)addr, __float_as_int(val));
  else            atomicMin((unsigned int*)addr, __float_as_uint(val));
}

// ---------------- init: stats=0, max buffers=-inf ----------------
__global__ void k_init(float* __restrict__ stats, float* __restrict__ maxb) {
  int i = threadIdx.x;
  if (i < 512) stats[i] = 0.f;
  if (i < 64)  maxb[i]  = -INFINITY;
}

// ---------------- GEMM1: h1 = x @ W_first + b, + BN partial stats ----------------
// wave-per-row, lane = output column; W (256x64) staged in LDS.
__global__ __launch_bounds__(256) void k_gemm1(
    const float* __restrict__ x, const float* __restrict__ W,
    const float* __restrict__ b, float* __restrict__ h1,
    float* __restrict__ stats, int rpb) {
  __shared__ float Wl[DF * HH];                       // 64 KiB
  for (int i = threadIdx.x; i < DF * HH / 4; i += 256)
    ((float4*)Wl)[i] = ((const float4*)W)[i];
  __syncthreads();

  const int lane = threadIdx.x & 63;
  const int wid  = threadIdx.x >> 6;
  const float bc = b[lane];
  int r0 = blockIdx.x * rpb;
  int r1 = min(r0 + rpb, NN);
  float ps = 0.f, pss = 0.f;

  for (int r = r0 + wid; r < r1; r += 4) {
    const float4* xr = (const float4*)(x + (size_t)r * DF);
    float acc = 0.f;
#pragma unroll 8
    for (int k4 = 0; k4 < DF / 4; ++k4) {
      float4 xv = xr[k4];
      acc = fmaf(xv.x, Wl[(k4 * 4 + 0) * HH + lane], acc);
      acc = fmaf(xv.y, Wl[(k4 * 4 + 1) * HH + lane], acc);
      acc = fmaf(xv.z, Wl[(k4 * 4 + 2) * HH + lane], acc);
      acc = fmaf(xv.w, Wl[(k4 * 4 + 3) * HH + lane], acc);
    }
    float h = acc + bc;
    h1[(size_t)r * HH + lane] = h;
    ps += h; pss += h * h;
  }
  atomicAdd(&stats[lane], ps);
  atomicAdd(&stats[HH + lane], pss);
}

// ---------------- BN finalize: fold mean/var/gamma/beta into scale+shift ----------------
__global__ void k_finalize_bn(const float* __restrict__ sums,
                              const float* __restrict__ gamma,
                              const float* __restrict__ beta,
                              float* __restrict__ ab) {
  int c = threadIdx.x;                                // 64 threads
  float mu  = sums[c] * (1.f / NN);
  float var = sums[HH + c] * (1.f / NN) - mu * mu;
  float a = gamma[c] * rsqrtf(var + BN_EPS);
  ab[c] = a;
  ab[HH + c] = beta[c] - mu * a;
}

// ---------------- normalize+ReLU (in place) + head (64->4) + graph max-pool ----------------
template <int ADDOUT>
__global__ __launch_bounds__(256) void k_norm_np(
    const float* __restrict__ hin, float* __restrict__ fout,
    const float* __restrict__ ab, const float* __restrict__ Wlin,
    const float* __restrict__ blin, const int* __restrict__ batch,
    float* __restrict__ node_pred, float* __restrict__ maxbuf, int rpb) {
  __shared__ float lmax[GG * TT];
  if (threadIdx.x < GG * TT) lmax[threadIdx.x] = -INFINITY;
  __syncthreads();

  const int lane = threadIdx.x & 63;
  const int wid  = threadIdx.x >> 6;
  const float a  = ab[lane];
  const float b2 = ab[HH + lane];
  const float4 w = ((const float4*)Wlin)[lane];       // W[lane][0..3]
  const float4 bl = *(const float4*)blin;
  int r0 = blockIdx.x * rpb;
  int r1 = min(r0 + rpb, NN);

  for (int r = r0 + wid; r < r1; r += 4) {
    float h = hin[(size_t)r * HH + lane];
    float f = fmaxf(fmaf(a, h, b2), 0.f);
    fout[(size_t)r * HH + lane] = f;
    float p0 = f * w.x, p1 = f * w.y, p2 = f * w.z, p3 = f * w.w;
#pragma unroll
    for (int off = 32; off; off >>= 1) {
      p0 += __shfl_xor(p0, off);
      p1 += __shfl_xor(p1, off);
      p2 += __shfl_xor(p2, off);
      p3 += __shfl_xor(p3, off);
    }
    if (lane == 0) {
      float4 np;
      np.x = p0 + bl.x; np.y = p1 + bl.y; np.z = p2 + bl.z; np.w = p3 + bl.w;
      int g = batch[r];
      atomicMaxF(&lmax[g * TT + 0], np.x);
      atomicMaxF(&lmax[g * TT + 1], np.y);
      atomicMaxF(&lmax[g * TT + 2], np.z);
      atomicMaxF(&lmax[g * TT + 3], np.w);
      float4* op = (float4*)(node_pred + (size_t)r * TT);
      if (ADDOUT) {
        float4 o = *op;
        np.x += o.x; np.y += o.y; np.z += o.z; np.w += o.w;
      }
      *op = np;
    }
  }
  __syncthreads();
  if (threadIdx.x < GG * TT) atomicMaxF(&maxbuf[threadIdx.x], lmax[threadIdx.x]);
}

// ---------------- edge scatter: agg[dst] += f[src] ----------------
__global__ __launch_bounds__(256) void k_edge_scatter(
    const int* __restrict__ ei, const float* __restrict__ f,
    float* __restrict__ agg) {
  const int lane = threadIdx.x & 63;
  int w  = (blockIdx.x * blockDim.x + threadIdx.x) >> 6;
  int nw = (gridDim.x * blockDim.x) >> 6;
  for (int e = w; e < NE; e += nw) {
    int src = ei[e];
    int dst = ei[NE + e];
    float v = f[(size_t)src * HH + lane];
    atomicAdd(&agg[(size_t)dst * HH + lane], v);
  }
}

// ---------------- GEMM2: h2 = (f+agg) @ W_conv + b, + BN partial stats ----------------
__global__ __launch_bounds__(256) void k_gemm2(
    const float* __restrict__ f, const float* __restrict__ agg,
    const float* __restrict__ W, const float* __restrict__ b,
    float* __restrict__ h2, float* __restrict__ stats, int rpb) {
  __shared__ float Wl[HH * HH];                       // 16 KiB
  for (int i = threadIdx.x; i < HH * HH / 4; i += 256)
    ((float4*)Wl)[i] = ((const float4*)W)[i];
  __syncthreads();

  const int lane = threadIdx.x & 63;
  const int wid  = threadIdx.x >> 6;
  const float bc = b[lane];
  int r0 = blockIdx.x * rpb;
  int r1 = min(r0 + rpb, NN);
  float ps = 0.f, pss = 0.f;

  for (int r = r0 + wid; r < r1; r += 4) {
    size_t base = (size_t)r * HH + lane;
    float v = f[base] + agg[base];
    float acc = 0.f;
#pragma unroll
    for (int k = 0; k < HH; ++k) {
      float s = __uint_as_float(__builtin_amdgcn_readlane(__float_as_uint(v), k));
      acc = fmaf(s, Wl[k * HH + lane], acc);
    }
    float h = acc + bc;
    h2[base] = h;
    ps += h; pss += h * h;
  }
  atomicAdd(&stats[lane], ps);
  atomicAdd(&stats[HH + lane], pss);
}

// ---------------- final: wsi = max0 + max1 ----------------
__global__ void k_wsi(const float* __restrict__ m0, const float* __restrict__ m1,
                      float* __restrict__ out) {
  int i = threadIdx.x;                                // 32 threads
  out[i] = m0[i] + m1[i];
}

extern "C" void kernel_launch(void* const* d_in, const int* in_sizes, int n_in,
                              void* d_out, int out_size, void* d_ws, size_t ws_size,
                              hipStream_t stream) {
  const float* x    = (const float*)d_in[0];
  const int*   ei   = (const int*)d_in[1];
  const int*   bat  = (const int*)d_in[2];
  const float* Wf   = (const float*)d_in[3];
  const float* bf   = (const float*)d_in[4];
  const float* g1   = (const float*)d_in[5];
  const float* be1  = (const float*)d_in[6];
  const float* Wl0  = (const float*)d_in[7];
  const float* bl0  = (const float*)d_in[8];
  const float* Wc   = (const float*)d_in[9];
  const float* bc   = (const float*)d_in[10];
  const float* g2   = (const float*)d_in[11];
  const float* be2  = (const float*)d_in[12];
  const float* Wl1  = (const float*)d_in[13];
  const float* bl1  = (const float*)d_in[14];

  float* out   = (float*)d_out;
  float* wsi   = out;                 // [8,4]
  float* npred = out + GG * TT;       // [N,4]

  float* ws     = (float*)d_ws;
  float* fbuf   = ws;                         // N*H   (h1 -> f in place)
  float* agg    = fbuf + (size_t)NN * HH;     // N*H
  float* h2     = agg  + (size_t)NN * HH;     // N*H   (h2 -> f2 in place)
  float* stats1 = h2   + (size_t)NN * HH;     // 256: sum(64) sumsq(64) a(64) b2(64)
  float* stats2 = stats1 + 256;               // 256
  float* maxb   = stats2 + 256;               // 64: max0(32) max1(32)

  int rpb = (NN + 511) / 512;                 // rows per block

  hipMemsetAsync(agg, 0, (size_t)NN * HH * sizeof(float), stream);
  k_init<<<dim3(1), dim3(512), 0, stream>>>(stats1, maxb);

  // Layer 0
  k_gemm1<<<dim3(512), dim3(256), 0, stream>>>(x, Wf, bf, fbuf, stats1, rpb);
  k_finalize_bn<<<dim3(1), dim3(64), 0, stream>>>(stats1, g1, be1, stats1 + 128);
  k_norm_np<0><<<dim3(512), dim3(256), 0, stream>>>(
      fbuf, fbuf, stats1 + 128, Wl0, bl0, bat, npred, maxb, rpb);

  // Layer 1: GIN aggregation + MLP
  k_edge_scatter<<<dim3(2048), dim3(256), 0, stream>>>(ei, fbuf, agg);
  k_gemm2<<<dim3(512), dim3(256), 0, stream>>>(fbuf, agg, Wc, bc, h2, stats2, rpb);
  k_finalize_bn<<<dim3(1), dim3(64), 0, stream>>>(stats2, g2, be2, stats2 + 128);
  k_norm_np<1><<<dim3(512), dim3(256), 0, stream>>>(
      h2, h2, stats2 + 128, Wl1, bl1, bat, npred, maxb + 32, rpb);

  k_wsi<<<dim3(1), dim3(32), 0, stream>>>(maxb, maxb + 32, wsi);
}

// Round 2
// 764.294 us; speedup vs baseline: 1.0094x; 1.0094x over previous
//
#include <hip/hip_runtime.h>
#include <math.h>

#define NN 100000
#define NE 1600000
#define DF 256
#define HH 64
#define TT 4
#define GG 8
#define BN_EPS 1e-5f

#define SCAN_BLK 1024
#define NB_SCAN ((NN + SCAN_BLK - 1) / SCAN_BLK)   // 98

__device__ __forceinline__ void atomicMaxF(float* addr, float val) {
  if (val >= 0.f) atomicMax((int*)addr, __float_as_int(val));
  else            atomicMin((unsigned int*)addr, __float_as_uint(val));
}

__device__ __forceinline__ float bcast(float v, int k) {
  return __uint_as_float(__builtin_amdgcn_readlane(__float_as_uint(v), k));
}

// ---------------- init: stats=0, max buffers=-inf ----------------
__global__ void k_init(float* __restrict__ stats, float* __restrict__ maxb) {
  int i = threadIdx.x;
  if (i < 512) stats[i] = 0.f;
  if (i < 64)  maxb[i]  = -INFINITY;
}

// ---------------- GEMM1: h1 = x @ W_first + b, + BN partial stats ----------------
// wave handles 8 rows at a time; lane = output column; W (256x64) in LDS.
// Each ds_read of W now serves 8 FMAs (was 1:1 -> LDS-issue-bound).
__global__ __launch_bounds__(256) void k_gemm1(
    const float* __restrict__ x, const float* __restrict__ W,
    const float* __restrict__ b, float* __restrict__ h1,
    float* __restrict__ stats, int rpb) {
  __shared__ float Wl[DF * HH];                       // 64 KiB
  for (int i = threadIdx.x; i < DF * HH / 4; i += 256)
    ((float4*)Wl)[i] = ((const float4*)W)[i];
  __syncthreads();

  const int lane = threadIdx.x & 63;
  const int wid  = threadIdx.x >> 6;
  const float bc = b[lane];
  int r0 = blockIdx.x * rpb;            // rpb = 224 (mult of 32); NN % 32 == 0
  int r1 = min(r0 + rpb, NN);
  float ps = 0.f, pss = 0.f;

  for (int rb = r0 + wid * 8; rb < r1; rb += 32) {
    float acc[8];
#pragma unroll
    for (int j = 0; j < 8; ++j) acc[j] = bc;
    const float4* xr = (const float4*)(x + (size_t)rb * DF);
#pragma unroll 4
    for (int k4 = 0; k4 < DF / 4; ++k4) {
      float w0 = Wl[(k4 * 4 + 0) * HH + lane];
      float w1 = Wl[(k4 * 4 + 1) * HH + lane];
      float w2 = Wl[(k4 * 4 + 2) * HH + lane];
      float w3 = Wl[(k4 * 4 + 3) * HH + lane];
#pragma unroll
      for (int j = 0; j < 8; ++j) {
        float4 xv = xr[j * (DF / 4) + k4];           // wave-uniform -> s_load
        acc[j] = fmaf(xv.x, w0, acc[j]);
        acc[j] = fmaf(xv.y, w1, acc[j]);
        acc[j] = fmaf(xv.z, w2, acc[j]);
        acc[j] = fmaf(xv.w, w3, acc[j]);
      }
    }
#pragma unroll
    for (int j = 0; j < 8; ++j) {
      float h = acc[j];
      h1[(size_t)(rb + j) * HH + lane] = h;
      ps += h; pss += h * h;
    }
  }
  atomicAdd(&stats[lane], ps);
  atomicAdd(&stats[HH + lane], pss);
}

// ---------------- BN finalize: fold mean/var/gamma/beta into scale+shift ----------------
__global__ void k_finalize_bn(const float* __restrict__ sums,
                              const float* __restrict__ gamma,
                              const float* __restrict__ beta,
                              float* __restrict__ ab) {
  int c = threadIdx.x;                                // 64 threads
  float mu  = sums[c] * (1.f / NN);
  float var = sums[HH + c] * (1.f / NN) - mu * mu;
  float a = gamma[c] * rsqrtf(var + BN_EPS);
  ab[c] = a;
  ab[HH + c] = beta[c] - mu * a;
}

// ---------------- normalize+ReLU (in place) + head (64->4) + graph max-pool ----------------
template <int ADDOUT>
__global__ __launch_bounds__(256) void k_norm_np(
    const float* __restrict__ hin, float* __restrict__ fout,
    const float* __restrict__ ab, const float* __restrict__ Wlin,
    const float* __restrict__ blin, const int* __restrict__ batch,
    float* __restrict__ node_pred, float* __restrict__ maxbuf, int rpb) {
  __shared__ float lmax[GG * TT];
  if (threadIdx.x < GG * TT) lmax[threadIdx.x] = -INFINITY;
  __syncthreads();

  const int lane = threadIdx.x & 63;
  const int wid  = threadIdx.x >> 6;
  const float a  = ab[lane];
  const float b2 = ab[HH + lane];
  const float4 w = ((const float4*)Wlin)[lane];       // W[lane][0..3]
  const float4 bl = *(const float4*)blin;
  int r0 = blockIdx.x * rpb;
  int r1 = min(r0 + rpb, NN);

  for (int r = r0 + wid; r < r1; r += 4) {
    float h = hin[(size_t)r * HH + lane];
    float f = fmaxf(fmaf(a, h, b2), 0.f);
    fout[(size_t)r * HH + lane] = f;
    float p0 = f * w.x, p1 = f * w.y, p2 = f * w.z, p3 = f * w.w;
#pragma unroll
    for (int off = 32; off; off >>= 1) {
      p0 += __shfl_xor(p0, off);
      p1 += __shfl_xor(p1, off);
      p2 += __shfl_xor(p2, off);
      p3 += __shfl_xor(p3, off);
    }
    if (lane == 0) {
      float4 np;
      np.x = p0 + bl.x; np.y = p1 + bl.y; np.z = p2 + bl.z; np.w = p3 + bl.w;
      int g = batch[r];
      atomicMaxF(&lmax[g * TT + 0], np.x);
      atomicMaxF(&lmax[g * TT + 1], np.y);
      atomicMaxF(&lmax[g * TT + 2], np.z);
      atomicMaxF(&lmax[g * TT + 3], np.w);
      float4* op = (float4*)(node_pred + (size_t)r * TT);
      if (ADDOUT) {
        float4 o = *op;
        np.x += o.x; np.y += o.y; np.z += o.z; np.w += o.w;
      }
      *op = np;
    }
  }
  __syncthreads();
  if (threadIdx.x < GG * TT) atomicMaxF(&maxbuf[threadIdx.x], lmax[threadIdx.x]);
}

// ---------------- CSR build: histogram ----------------
__global__ __launch_bounds__(256) void k_count(const int* __restrict__ ei,
                                               int* __restrict__ deg) {
  int i = blockIdx.x * blockDim.x + threadIdx.x;
  int n = gridDim.x * blockDim.x;
  for (int e = i; e < NE; e += n) atomicAdd(&deg[ei[NE + e]], 1);
}

// ---------------- CSR build: 3-kernel exclusive scan ----------------
__global__ __launch_bounds__(256) void k_scanA(const int* __restrict__ deg,
                                               int* __restrict__ rowstart,
                                               int* __restrict__ bsum) {
  __shared__ int s[256];
  int t = threadIdx.x;
  int base = blockIdx.x * SCAN_BLK + t * 4;
  int d0 = 0, d1 = 0, d2 = 0, d3 = 0;
  if (base + 3 < NN) {
    int4 v = *(const int4*)(deg + base);
    d0 = v.x; d1 = v.y; d2 = v.z; d3 = v.w;
  } else {
    if (base + 0 < NN) d0 = deg[base + 0];
    if (base + 1 < NN) d1 = deg[base + 1];
    if (base + 2 < NN) d2 = deg[base + 2];
    if (base + 3 < NN) d3 = deg[base + 3];
  }
  int ts = d0 + d1 + d2 + d3;
  s[t] = ts;
  __syncthreads();
  for (int off = 1; off < 256; off <<= 1) {
    int v = (t >= off) ? s[t - off] : 0;
    __syncthreads();
    s[t] += v;
    __syncthreads();
  }
  int excl = s[t] - ts;                  // block-local exclusive prefix
  if (base + 0 < NN) rowstart[base + 0] = excl;  excl += d0;
  if (base + 1 < NN) rowstart[base + 1] = excl;  excl += d1;
  if (base + 2 < NN) rowstart[base + 2] = excl;  excl += d2;
  if (base + 3 < NN) rowstart[base + 3] = excl;
  if (t == 255) bsum[blockIdx.x] = s[255];
}

__global__ void k_scanB(const int* __restrict__ bsum, int* __restrict__ bscan) {
  __shared__ int s[128];
  int t = threadIdx.x;                   // 128 threads
  int v = (t < NB_SCAN) ? bsum[t] : 0;
  s[t] = v;
  __syncthreads();
  for (int off = 1; off < 128; off <<= 1) {
    int u = (t >= off) ? s[t - off] : 0;
    __syncthreads();
    s[t] += u;
    __syncthreads();
  }
  if (t < NB_SCAN) bscan[t] = s[t] - v;
}

__global__ __launch_bounds__(256) void k_scanC(int* __restrict__ rowstart,
                                               const int* __restrict__ bscan,
                                               int* __restrict__ cursor) {
  int off = bscan[blockIdx.x];
  int base = blockIdx.x * SCAN_BLK + threadIdx.x * 4;
#pragma unroll
  for (int j = 0; j < 4; ++j) {
    int i = base + j;
    if (i < NN) {
      int r = rowstart[i] + off;
      rowstart[i] = r;
      cursor[i] = r;
    }
  }
}

// ---------------- CSR build: fill src lists ----------------
__global__ __launch_bounds__(256) void k_fill(const int* __restrict__ ei,
                                              int* __restrict__ cursor,
                                              int* __restrict__ srcl) {
  int i = blockIdx.x * blockDim.x + threadIdx.x;
  int n = gridDim.x * blockDim.x;
  for (int e = i; e < NE; e += n) {
    int src = ei[e];
    int dst = ei[NE + e];
    int p = atomicAdd(&cursor[dst], 1);
    srcl[p] = src;
  }
}

// ---------------- fused: gather (CSR) + GEMM2 + BN partial stats ----------------
__global__ __launch_bounds__(256) void k_gemm2f(
    const float* __restrict__ f, const int* __restrict__ rowstart,
    const int* __restrict__ deg, const int* __restrict__ srcl,
    const float* __restrict__ W, const float* __restrict__ b,
    float* __restrict__ h2, float* __restrict__ stats, int rpb) {
  __shared__ float Wl[HH * HH];                       // 16 KiB
  for (int i = threadIdx.x; i < HH * HH / 4; i += 256)
    ((float4*)Wl)[i] = ((const float4*)W)[i];
  __syncthreads();

  const int lane = threadIdx.x & 63;
  const int wid  = threadIdx.x >> 6;
  const float bc = b[lane];
  int r0 = blockIdx.x * rpb;            // rpb = 112 (mult of 16); NN % 16 == 0
  int r1 = min(r0 + rpb, NN);
  float ps = 0.f, pss = 0.f;

  for (int rb = r0 + wid * 4; rb < r1; rb += 16) {
    float v0, v1, v2, v3;
#define GATHER(J, VJ) { \
    int row = rb + (J); \
    float a = f[(size_t)row * HH + lane]; \
    int s0 = rowstart[row], d = deg[row]; \
    int e = 0; \
    for (; e + 4 <= d; e += 4) { \
      int i0 = srcl[s0+e], i1 = srcl[s0+e+1], i2 = srcl[s0+e+2], i3 = srcl[s0+e+3]; \
      float g0 = f[(size_t)i0*HH+lane], g1 = f[(size_t)i1*HH+lane]; \
      float g2 = f[(size_t)i2*HH+lane], g3 = f[(size_t)i3*HH+lane]; \
      a += g0 + g1 + g2 + g3; \
    } \
    for (; e < d; ++e) a += f[(size_t)srcl[s0+e]*HH+lane]; \
    VJ = a; }
    GATHER(0, v0) GATHER(1, v1) GATHER(2, v2) GATHER(3, v3)
#undef GATHER
    float a0 = bc, a1 = bc, a2 = bc, a3 = bc;
#pragma unroll 8
    for (int k = 0; k < HH; ++k) {
      float w = Wl[k * HH + lane];
      a0 = fmaf(bcast(v0, k), w, a0);
      a1 = fmaf(bcast(v1, k), w, a1);
      a2 = fmaf(bcast(v2, k), w, a2);
      a3 = fmaf(bcast(v3, k), w, a3);
    }
    h2[(size_t)(rb + 0) * HH + lane] = a0; ps += a0; pss += a0 * a0;
    h2[(size_t)(rb + 1) * HH + lane] = a1; ps += a1; pss += a1 * a1;
    h2[(size_t)(rb + 2) * HH + lane] = a2; ps += a2; pss += a2 * a2;
    h2[(size_t)(rb + 3) * HH + lane] = a3; ps += a3; pss += a3 * a3;
  }
  atomicAdd(&stats[lane], ps);
  atomicAdd(&stats[HH + lane], pss);
}

// ---------------- final: wsi = max0 + max1 ----------------
__global__ void k_wsi(const float* __restrict__ m0, const float* __restrict__ m1,
                      float* __restrict__ out) {
  int i = threadIdx.x;                                // 32 threads
  out[i] = m0[i] + m1[i];
}

extern "C" void kernel_launch(void* const* d_in, const int* in_sizes, int n_in,
                              void* d_out, int out_size, void* d_ws, size_t ws_size,
                              hipStream_t stream) {
  const float* x    = (const float*)d_in[0];
  const int*   ei   = (const int*)d_in[1];
  const int*   bat  = (const int*)d_in[2];
  const float* Wf   = (const float*)d_in[3];
  const float* bf   = (const float*)d_in[4];
  const float* g1   = (const float*)d_in[5];
  const float* be1  = (const float*)d_in[6];
  const float* Wl0  = (const float*)d_in[7];
  const float* bl0  = (const float*)d_in[8];
  const float* Wc   = (const float*)d_in[9];
  const float* bc   = (const float*)d_in[10];
  const float* g2   = (const float*)d_in[11];
  const float* be2  = (const float*)d_in[12];
  const float* Wl1  = (const float*)d_in[13];
  const float* bl1  = (const float*)d_in[14];

  float* out   = (float*)d_out;
  float* wsi   = out;                 // [8,4]
  float* npred = out + GG * TT;       // [N,4]

  float* ws     = (float*)d_ws;
  float* fbuf   = ws;                         // N*H
  float* h2     = fbuf + (size_t)NN * HH;     // N*H
  float* stats1 = h2 + (size_t)NN * HH;       // 256
  float* stats2 = stats1 + 256;               // 256
  float* maxb   = stats2 + 256;               // 64
  int*   deg      = (int*)(maxb + 64);        // N
  int*   rowstart = deg + NN;                 // N
  int*   cursor   = rowstart + NN;            // N
  int*   bsum     = cursor + NN;              // 128
  int*   bscan    = bsum + 128;               // 128
  int*   srcl     = bscan + 128;              // NE

  hipMemsetAsync(deg, 0, NN * sizeof(int), stream);
  k_init<<<dim3(1), dim3(512), 0, stream>>>(stats1, maxb);

  // CSR build (independent of layer 0 math)
  k_count<<<dim3(1024), dim3(256), 0, stream>>>(ei, deg);
  k_scanA<<<dim3(NB_SCAN), dim3(256), 0, stream>>>(deg, rowstart, bsum);
  k_scanB<<<dim3(1), dim3(128), 0, stream>>>(bsum, bscan);
  k_scanC<<<dim3(NB_SCAN), dim3(256), 0, stream>>>(rowstart, bscan, cursor);
  k_fill<<<dim3(1024), dim3(256), 0, stream>>>(ei, cursor, srcl);

  // Layer 0
  {
    int rpb = 224;                            // mult of 32
    int nb = (NN + rpb - 1) / rpb;            // 447
    k_gemm1<<<dim3(nb), dim3(256), 0, stream>>>(x, Wf, bf, fbuf, stats1, rpb);
  }
  k_finalize_bn<<<dim3(1), dim3(64), 0, stream>>>(stats1, g1, be1, stats1 + 128);
  k_norm_np<0><<<dim3(512), dim3(256), 0, stream>>>(
      fbuf, fbuf, stats1 + 128, Wl0, bl0, bat, npred, maxb, (NN + 511) / 512);

  // Layer 1: fused gather + GEMM
  {
    int rpb = 112;                            // mult of 16
    int nb = (NN + rpb - 1) / rpb;            // 893
    k_gemm2f<<<dim3(nb), dim3(256), 0, stream>>>(
        fbuf, rowstart, deg, srcl, Wc, bc, h2, stats2, rpb);
  }
  k_finalize_bn<<<dim3(1), dim3(64), 0, stream>>>(stats2, g2, be2, stats2 + 128);
  k_norm_np<1><<<dim3(512), dim3(256), 0, stream>>>(
      h2, h2, stats2 + 128, Wl1, bl1, bat, npred, maxb + 32, (NN + 511) / 512);

  k_wsi<<<dim3(1), dim3(32), 0, stream>>>(maxb, maxb + 32, wsi);
}

// Round 3
// 586.781 us; speedup vs baseline: 1.3148x; 1.3025x over previous
//
#include <hip/hip_runtime.h>
#include <math.h>

#define NN 100000
#define NE 1600000
#define DF 256
#define HH 64
#define TT 4
#define GG 8
#define BN_EPS 1e-5f

#define SCAN_BLK 1024
#define NB_SCAN ((NN + SCAN_BLK - 1) / SCAN_BLK)   // 98

typedef __attribute__((ext_vector_type(8))) short short8v;
typedef __attribute__((ext_vector_type(4))) float f32x4;
typedef unsigned short ushort_t;
typedef unsigned int uint_t;

__device__ __forceinline__ void atomicMaxF(float* addr, float val) {
  if (val >= 0.f) atomicMax((int*)addr, __float_as_int(val));
  else            atomicMin((unsigned int*)addr, __float_as_uint(val));
}

__device__ __forceinline__ float bcast(float v, int k) {
  return __uint_as_float(__builtin_amdgcn_readlane(__float_as_uint(v), k));
}

// fp32 -> bf16 bits, round-to-nearest-even
__device__ __forceinline__ short f2bf(float f) {
  uint_t u = __float_as_uint(f);
  u += 0x7FFFu + ((u >> 16) & 1u);
  return (short)(u >> 16);
}

// ---------------- init: stats=0, max buffers=-inf ----------------
__global__ void k_init(float* __restrict__ stats, float* __restrict__ maxb) {
  int i = threadIdx.x;
  if (i < 512) stats[i] = 0.f;
  if (i < 64)  maxb[i]  = -INFINITY;
}

// ---------------- prep: W_first fp32 -> bf16 bits ----------------
__global__ void k_prep(const float* __restrict__ W, ushort_t* __restrict__ Wbf) {
  int i = blockIdx.x * 256 + threadIdx.x;          // 64 blocks x 256 = 16384
  Wbf[i] = (ushort_t)f2bf(W[i]);
}

// ---------------- GEMM1 (MFMA bf16): h1 = x @ W_first + b, + BN stats ----------------
// LDS-free. W (256x64) lives in registers as 8 k-steps x 4 col-tiles of B-frags.
// Verified gfx950 16x16x32 layouts: A: lane->(row=l&15, k=8*(l>>4)+e);
// B: lane->(col=l&15, k=8*(l>>4)+e); D: lane,reg->(row=(l>>4)*4+r, col=l&15).
__global__ __launch_bounds__(256, 2) void k_gemm1_mfma(
    const float* __restrict__ x, const ushort_t* __restrict__ Wbf,
    const float* __restrict__ b, float* __restrict__ h1,
    float* __restrict__ stats) {
  const int lane = threadIdx.x & 63;
  const int li = lane & 15;
  const int lh = lane >> 4;
  const int gw = (blockIdx.x * 256 + (int)threadIdx.x) >> 6;
  const int nw = (gridDim.x * 256) >> 6;

  short8v bf[8][4];
#pragma unroll
  for (int s = 0; s < 8; ++s)
#pragma unroll
    for (int ct = 0; ct < 4; ++ct)
#pragma unroll
      for (int e = 0; e < 8; ++e)
        bf[s][ct][e] = (short)Wbf[(32 * s + 8 * lh + e) * HH + ct * 16 + li];

  float bias[4];
#pragma unroll
  for (int ct = 0; ct < 4; ++ct) bias[ct] = b[ct * 16 + li];

  float ps[4] = {0.f, 0.f, 0.f, 0.f}, pss[4] = {0.f, 0.f, 0.f, 0.f};

  for (int t = gw; t < NN / 16; t += nw) {
    const float* xb = x + (size_t)(t * 16 + li) * DF + 8 * lh;
    f32x4 acc[4];
#pragma unroll
    for (int ct = 0; ct < 4; ++ct) acc[ct] = (f32x4){0.f, 0.f, 0.f, 0.f};

#pragma unroll
    for (int s = 0; s < 8; ++s) {
      float4 a0 = *(const float4*)(xb + 32 * s);
      float4 a1 = *(const float4*)(xb + 32 * s + 4);
      short8v af;
      af[0] = f2bf(a0.x); af[1] = f2bf(a0.y); af[2] = f2bf(a0.z); af[3] = f2bf(a0.w);
      af[4] = f2bf(a1.x); af[5] = f2bf(a1.y); af[6] = f2bf(a1.z); af[7] = f2bf(a1.w);
#pragma unroll
      for (int ct = 0; ct < 4; ++ct)
        acc[ct] = __builtin_amdgcn_mfma_f32_16x16x32_bf16(af, bf[s][ct], acc[ct], 0, 0, 0);
    }

    float* hb = h1 + (size_t)t * 16 * HH;
#pragma unroll
    for (int ct = 0; ct < 4; ++ct) {
#pragma unroll
      for (int r = 0; r < 4; ++r) {
        float h = acc[ct][r] + bias[ct];
        hb[(lh * 4 + r) * HH + ct * 16 + li] = h;
        ps[ct] += h; pss[ct] += h * h;
      }
    }
  }

#pragma unroll
  for (int ct = 0; ct < 4; ++ct) {
    ps[ct]  += __shfl_xor(ps[ct], 16);  ps[ct]  += __shfl_xor(ps[ct], 32);
    pss[ct] += __shfl_xor(pss[ct], 16); pss[ct] += __shfl_xor(pss[ct], 32);
  }
  if (lane < 16) {
#pragma unroll
    for (int ct = 0; ct < 4; ++ct) {
      atomicAdd(&stats[ct * 16 + lane], ps[ct]);
      atomicAdd(&stats[HH + ct * 16 + lane], pss[ct]);
    }
  }
}

// ---------------- BN finalize: fold mean/var/gamma/beta into scale+shift ----------------
__global__ void k_finalize_bn(const float* __restrict__ sums,
                              const float* __restrict__ gamma,
                              const float* __restrict__ beta,
                              float* __restrict__ ab) {
  int c = threadIdx.x;                                // 64 threads
  float mu  = sums[c] * (1.f / NN);
  float var = sums[HH + c] * (1.f / NN) - mu * mu;
  float a = gamma[c] * rsqrtf(var + BN_EPS);
  ab[c] = a;
  ab[HH + c] = beta[c] - mu * a;
}

// ---------------- normalize+ReLU (in place) + head (64->4) + graph max-pool ----------------
template <int ADDOUT>
__global__ __launch_bounds__(256) void k_norm_np(
    const float* __restrict__ hin, float* __restrict__ fout,
    const float* __restrict__ ab, const float* __restrict__ Wlin,
    const float* __restrict__ blin, const int* __restrict__ batch,
    float* __restrict__ node_pred, float* __restrict__ maxbuf, int rpb) {
  __shared__ float lmax[GG * TT];
  if (threadIdx.x < GG * TT) lmax[threadIdx.x] = -INFINITY;
  __syncthreads();

  const int lane = threadIdx.x & 63;
  const int wid  = threadIdx.x >> 6;
  const float a  = ab[lane];
  const float b2 = ab[HH + lane];
  const float4 w = ((const float4*)Wlin)[lane];       // W[lane][0..3]
  const float4 bl = *(const float4*)blin;
  int r0 = blockIdx.x * rpb;
  int r1 = min(r0 + rpb, NN);

  for (int r = r0 + wid; r < r1; r += 4) {
    float h = hin[(size_t)r * HH + lane];
    float f = fmaxf(fmaf(a, h, b2), 0.f);
    fout[(size_t)r * HH + lane] = f;
    float p0 = f * w.x, p1 = f * w.y, p2 = f * w.z, p3 = f * w.w;
#pragma unroll
    for (int off = 32; off; off >>= 1) {
      p0 += __shfl_xor(p0, off);
      p1 += __shfl_xor(p1, off);
      p2 += __shfl_xor(p2, off);
      p3 += __shfl_xor(p3, off);
    }
    if (lane == 0) {
      float4 np;
      np.x = p0 + bl.x; np.y = p1 + bl.y; np.z = p2 + bl.z; np.w = p3 + bl.w;
      int g = batch[r];
      atomicMaxF(&lmax[g * TT + 0], np.x);
      atomicMaxF(&lmax[g * TT + 1], np.y);
      atomicMaxF(&lmax[g * TT + 2], np.z);
      atomicMaxF(&lmax[g * TT + 3], np.w);
      float4* op = (float4*)(node_pred + (size_t)r * TT);
      if (ADDOUT) {
        float4 o = *op;
        np.x += o.x; np.y += o.y; np.z += o.z; np.w += o.w;
      }
      *op = np;
    }
  }
  __syncthreads();
  if (threadIdx.x < GG * TT) atomicMaxF(&maxbuf[threadIdx.x], lmax[threadIdx.x]);
}

// ---------------- CSR build: histogram ----------------
__global__ __launch_bounds__(256) void k_count(const int* __restrict__ ei,
                                               int* __restrict__ deg) {
  int i = blockIdx.x * blockDim.x + threadIdx.x;
  int n = gridDim.x * blockDim.x;
  for (int e = i; e < NE; e += n) atomicAdd(&deg[ei[NE + e]], 1);
}

// ---------------- CSR build: 3-kernel exclusive scan ----------------
__global__ __launch_bounds__(256) void k_scanA(const int* __restrict__ deg,
                                               int* __restrict__ rowstart,
                                               int* __restrict__ bsum) {
  __shared__ int s[256];
  int t = threadIdx.x;
  int base = blockIdx.x * SCAN_BLK + t * 4;
  int d0 = 0, d1 = 0, d2 = 0, d3 = 0;
  if (base + 3 < NN) {
    int4 v = *(const int4*)(deg + base);
    d0 = v.x; d1 = v.y; d2 = v.z; d3 = v.w;
  } else {
    if (base + 0 < NN) d0 = deg[base + 0];
    if (base + 1 < NN) d1 = deg[base + 1];
    if (base + 2 < NN) d2 = deg[base + 2];
    if (base + 3 < NN) d3 = deg[base + 3];
  }
  int ts = d0 + d1 + d2 + d3;
  s[t] = ts;
  __syncthreads();
  for (int off = 1; off < 256; off <<= 1) {
    int v = (t >= off) ? s[t - off] : 0;
    __syncthreads();
    s[t] += v;
    __syncthreads();
  }
  int excl = s[t] - ts;                  // block-local exclusive prefix
  if (base + 0 < NN) rowstart[base + 0] = excl;  excl += d0;
  if (base + 1 < NN) rowstart[base + 1] = excl;  excl += d1;
  if (base + 2 < NN) rowstart[base + 2] = excl;  excl += d2;
  if (base + 3 < NN) rowstart[base + 3] = excl;
  if (t == 255) bsum[blockIdx.x] = s[255];
}

__global__ void k_scanB(const int* __restrict__ bsum, int* __restrict__ bscan) {
  __shared__ int s[128];
  int t = threadIdx.x;                   // 128 threads
  int v = (t < NB_SCAN) ? bsum[t] : 0;
  s[t] = v;
  __syncthreads();
  for (int off = 1; off < 128; off <<= 1) {
    int u = (t >= off) ? s[t - off] : 0;
    __syncthreads();
    s[t] += u;
    __syncthreads();
  }
  if (t < NB_SCAN) bscan[t] = s[t] - v;
}

__global__ __launch_bounds__(256) void k_scanC(int* __restrict__ rowstart,
                                               const int* __restrict__ bscan,
                                               int* __restrict__ cursor) {
  int off = bscan[blockIdx.x];
  int base = blockIdx.x * SCAN_BLK + threadIdx.x * 4;
#pragma unroll
  for (int j = 0; j < 4; ++j) {
    int i = base + j;
    if (i < NN) {
      int r = rowstart[i] + off;
      rowstart[i] = r;
      cursor[i] = r;
    }
  }
}

// ---------------- CSR build: fill src lists ----------------
__global__ __launch_bounds__(256) void k_fill(const int* __restrict__ ei,
                                              int* __restrict__ cursor,
                                              int* __restrict__ srcl) {
  int i = blockIdx.x * blockDim.x + threadIdx.x;
  int n = gridDim.x * blockDim.x;
  for (int e = i; e < NE; e += n) {
    int src = ei[e];
    int dst = ei[NE + e];
    int p = atomicAdd(&cursor[dst], 1);
    srcl[p] = src;
  }
}

// ---------------- fused: gather (CSR) + GEMM2 + BN partial stats ----------------
__global__ __launch_bounds__(256) void k_gemm2f(
    const float* __restrict__ f, const int* __restrict__ rowstart,
    const int* __restrict__ deg, const int* __restrict__ srcl,
    const float* __restrict__ W, const float* __restrict__ b,
    float* __restrict__ h2, float* __restrict__ stats, int rpb) {
  __shared__ float Wl[HH * HH];                       // 16 KiB
  for (int i = threadIdx.x; i < HH * HH / 4; i += 256)
    ((float4*)Wl)[i] = ((const float4*)W)[i];
  __syncthreads();

  const int lane = threadIdx.x & 63;
  const int wid  = threadIdx.x >> 6;
  const float bc = b[lane];
  int r0 = blockIdx.x * rpb;            // rpb = 112 (mult of 16); NN % 16 == 0
  int r1 = min(r0 + rpb, NN);
  float ps = 0.f, pss = 0.f;

  for (int rb = r0 + wid * 4; rb < r1; rb += 16) {
    float v0, v1, v2, v3;
#define GATHER(J, VJ) { \
    int row = rb + (J); \
    float a = f[(size_t)row * HH + lane]; \
    int s0 = rowstart[row], d = deg[row]; \
    int e = 0; \
    for (; e + 4 <= d; e += 4) { \
      int i0 = srcl[s0+e], i1 = srcl[s0+e+1], i2 = srcl[s0+e+2], i3 = srcl[s0+e+3]; \
      float g0 = f[(size_t)i0*HH+lane], g1 = f[(size_t)i1*HH+lane]; \
      float g2 = f[(size_t)i2*HH+lane], g3 = f[(size_t)i3*HH+lane]; \
      a += g0 + g1 + g2 + g3; \
    } \
    for (; e < d; ++e) a += f[(size_t)srcl[s0+e]*HH+lane]; \
    VJ = a; }
    GATHER(0, v0) GATHER(1, v1) GATHER(2, v2) GATHER(3, v3)
#undef GATHER
    float a0 = bc, a1 = bc, a2 = bc, a3 = bc;
#pragma unroll 8
    for (int k = 0; k < HH; ++k) {
      float w = Wl[k * HH + lane];
      a0 = fmaf(bcast(v0, k), w, a0);
      a1 = fmaf(bcast(v1, k), w, a1);
      a2 = fmaf(bcast(v2, k), w, a2);
      a3 = fmaf(bcast(v3, k), w, a3);
    }
    h2[(size_t)(rb + 0) * HH + lane] = a0; ps += a0; pss += a0 * a0;
    h2[(size_t)(rb + 1) * HH + lane] = a1; ps += a1; pss += a1 * a1;
    h2[(size_t)(rb + 2) * HH + lane] = a2; ps += a2; pss += a2 * a2;
    h2[(size_t)(rb + 3) * HH + lane] = a3; ps += a3; pss += a3 * a3;
  }
  atomicAdd(&stats[lane], ps);
  atomicAdd(&stats[HH + lane], pss);
}

// ---------------- final: wsi = max0 + max1 ----------------
__global__ void k_wsi(const float* __restrict__ m0, const float* __restrict__ m1,
                      float* __restrict__ out) {
  int i = threadIdx.x;                                // 32 threads
  out[i] = m0[i] + m1[i];
}

extern "C" void kernel_launch(void* const* d_in, const int* in_sizes, int n_in,
                              void* d_out, int out_size, void* d_ws, size_t ws_size,
                              hipStream_t stream) {
  const float* x    = (const float*)d_in[0];
  const int*   ei   = (const int*)d_in[1];
  const int*   bat  = (const int*)d_in[2];
  const float* Wf   = (const float*)d_in[3];
  const float* bf   = (const float*)d_in[4];
  const float* g1   = (const float*)d_in[5];
  const float* be1  = (const float*)d_in[6];
  const float* Wl0  = (const float*)d_in[7];
  const float* bl0  = (const float*)d_in[8];
  const float* Wc   = (const float*)d_in[9];
  const float* bc   = (const float*)d_in[10];
  const float* g2   = (const float*)d_in[11];
  const float* be2  = (const float*)d_in[12];
  const float* Wl1  = (const float*)d_in[13];
  const float* bl1  = (const float*)d_in[14];

  float* out   = (float*)d_out;
  float* wsi   = out;                 // [8,4]
  float* npred = out + GG * TT;       // [N,4]

  float* ws     = (float*)d_ws;
  float* fbuf   = ws;                         // N*H
  float* h2     = fbuf + (size_t)NN * HH;     // N*H
  float* stats1 = h2 + (size_t)NN * HH;       // 256
  float* stats2 = stats1 + 256;               // 256
  float* maxb   = stats2 + 256;               // 64
  int*   deg      = (int*)(maxb + 64);        // N
  int*   rowstart = deg + NN;                 // N
  int*   cursor   = rowstart + NN;            // N
  int*   bsum     = cursor + NN;              // 128
  int*   bscan    = bsum + 128;               // 128
  int*   srcl     = bscan + 128;              // NE
  ushort_t* Wbf   = (ushort_t*)(srcl + NE);   // DF*HH bf16 bits

  hipMemsetAsync(deg, 0, NN * sizeof(int), stream);
  k_init<<<dim3(1), dim3(512), 0, stream>>>(stats1, maxb);
  k_prep<<<dim3(64), dim3(256), 0, stream>>>(Wf, Wbf);

  // CSR build (independent of layer 0 math)
  k_count<<<dim3(1024), dim3(256), 0, stream>>>(ei, deg);
  k_scanA<<<dim3(NB_SCAN), dim3(256), 0, stream>>>(deg, rowstart, bsum);
  k_scanB<<<dim3(1), dim3(128), 0, stream>>>(bsum, bscan);
  k_scanC<<<dim3(NB_SCAN), dim3(256), 0, stream>>>(rowstart, bscan, cursor);
  k_fill<<<dim3(1024), dim3(256), 0, stream>>>(ei, cursor, srcl);

  // Layer 0: MFMA bf16 GEMM
  k_gemm1_mfma<<<dim3(512), dim3(256), 0, stream>>>(x, Wbf, bf, fbuf, stats1);
  k_finalize_bn<<<dim3(1), dim3(64), 0, stream>>>(stats1, g1, be1, stats1 + 128);
  k_norm_np<0><<<dim3(512), dim3(256), 0, stream>>>(
      fbuf, fbuf, stats1 + 128, Wl0, bl0, bat, npred, maxb, (NN + 511) / 512);

  // Layer 1: fused gather + GEMM
  {
    int rpb = 112;                            // mult of 16
    int nb = (NN + rpb - 1) / rpb;            // 893
    k_gemm2f<<<dim3(nb), dim3(256), 0, stream>>>(
        fbuf, rowstart, deg, srcl, Wc, bc, h2, stats2, rpb);
  }
  k_finalize_bn<<<dim3(1), dim3(64), 0, stream>>>(stats2, g2, be2, stats2 + 128);
  k_norm_np<1><<<dim3(512), dim3(256), 0, stream>>>(
      h2, h2, stats2 + 128, Wl1, bl1, bat, npred, maxb + 32, (NN + 511) / 512);

  k_wsi<<<dim3(1), dim3(32), 0, stream>>>(maxb, maxb + 32, wsi);
}